// Round 11
// baseline (249.331 us; speedup 1.0000x reference)
//
#include <hip/hip_runtime.h>
#include <hip/hip_bf16.h>

// B=2, L=2048, D=1024, H=16, Dh=64. fp32 in/out, int32 mask. ref = full-fp32 np.
//  K0 presplit: X,Wq,Wk -> (hi,lo) bf16; Wv -> bf16.
//  K1 qkv_gemm (R2 version, ~63-69us = ~900 TF, at m97-structure ceiling):
//     128x128 tile, 32 k-iters, 4-tensor staging (Xh,Xl,Wh,Wl) in 32KB LDS.
//     Fragment-dedup: 16 ds_read_b128/kt for 48 MFMA. V epilogue via wave-private
//     LDS transpose -> coalesced 16B stores. Q epilogue folds 2*log2e/8.
//  K2 attn DOUBLE-Q: 512-thread blocks (8 waves), each block owns 128 q-rows
//     (q0 = 128j), kb = 0..2j+1. K tile staging + barrier + K ds-reads amortized
//     over 2x q-rows -> per-CU iterations 66 -> 34 (R2 vs R7 showed attn is
//     CU-throughput-bound on per-iter cost with a large fixed component).
//     grid (32 bh, 16 Y): bh = blockIdx.x pins XCD (R8 lesson). Pair map
//     j = Y<8 ? Y : 23-Y -> co-resident {Y,Y+8} totals constant (34).
//     LDS 48KB (Khs16+Kls16+Ps16) -> 2 blocks/CU = 16 waves/CU.
//     Kh+Kl LDS dbuf XOR-swizzled (R2-verified); Ps LINEAR (R10: swizzle null);
//     bounded softmax p = e^{30 tanh(x)-30}; in-register normalize; f32 Out.
//  RULES: QK-side MFMA operands must be LDS-staged one iter ahead (R1/R8/R9:
//  per-iter global loads on that path = ~151us). No device fences (R4). No
//  launch_bounds below measured VGPR need (R5). Fixed ~55us inter-kernel
//  overhead, not per-launch (R6). Dynamic tile placement kills XCD L2 (R8).
//  MFMA C-layout: row=quad*4+reg, col=lane&15 [m89/m91]; A/B-layout: [lane&15][quad*8+j] [m120].

typedef unsigned short u16;
typedef __bf16 bf16x8 __attribute__((ext_vector_type(8)));
typedef float f32x4 __attribute__((ext_vector_type(4)));

#define MFMA(a, b, c) __builtin_amdgcn_mfma_f32_16x16x32_bf16(a, b, c, 0, 0, 0)

__device__ __forceinline__ u16 bf16rne(float f) {
    unsigned int u = __float_as_uint(f);
    u += 0x7fffu + ((u >> 16) & 1u);
    return (u16)(u >> 16);
}
__device__ __forceinline__ float bf16f(u16 h) {
    return __uint_as_float(((unsigned int)h) << 16);
}
__device__ __forceinline__ void split1(float f, u16& hi, u16& lo) {
    hi = bf16rne(f);
    lo = bf16rne(f - bf16f(hi));
}
__device__ __forceinline__ unsigned int pk2(float a, float b) {   // v_cvt_pk_bf16_f32 (RNE)
    __hip_bfloat162 t = __float22bfloat162_rn(float2{a, b});
    return *(unsigned int*)&t;
}
__device__ __forceinline__ float fexp2(float x) {                 // 2^x, raw v_exp_f32
#if __has_builtin(__builtin_amdgcn_exp2f)
    return __builtin_amdgcn_exp2f(x);
#else
    return __expf(x * 0.6931471805599453f);
#endif
}

// async global->LDS, 16B per lane. LDS dest must be uniform_base + lane*16.
__device__ __forceinline__ void gl16(const u16* g, u16* l) {
    __builtin_amdgcn_global_load_lds(
        (const __attribute__((address_space(1))) unsigned int*)g,
        (__attribute__((address_space(3))) unsigned int*)l, 16, 0, 0);
}

// ---------------- Kernel 0: pre-split fp32 -> bf16 hi/lo ----------------
__global__ __launch_bounds__(256) void presplit(
    const float* __restrict__ X, const float* __restrict__ Wq,
    const float* __restrict__ Wk, const float* __restrict__ Wv,
    u16* __restrict__ Xh, u16* __restrict__ Xl,
    u16* __restrict__ Wqh, u16* __restrict__ Wql,
    u16* __restrict__ Wkh, u16* __restrict__ Wkl,
    u16* __restrict__ Wvh)
{
    int i = blockIdx.x * 256 + threadIdx.x;
    const float* src; u16 *dh, *dl; int off;
    if (i < 1048576)      { src = X;  dh = Xh;  dl = Xl;      off = i; }
    else if (i < 1310720) { src = Wq; dh = Wqh; dl = Wql;     off = i - 1048576; }
    else if (i < 1572864) { src = Wk; dh = Wkh; dl = Wkl;     off = i - 1310720; }
    else                  { src = Wv; dh = Wvh; dl = nullptr; off = i - 1572864; }
    float4 v = ((const float4*)src)[off];
    ushort4 h, l;
    split1(v.x, h.x, l.x); split1(v.y, h.y, l.y);
    split1(v.z, h.z, l.z); split1(v.w, h.w, l.w);
    ((ushort4*)dh)[off] = h;
    if (dl) ((ushort4*)dl)[off] = l;
}

// ---------------- Kernel 1: QKV GEMM (4-tensor staging, frag-dedup) ----------------
// 768 blocks; swizzle keeps all m-blocks of one n-block on one XCD.
__global__ __launch_bounds__(256, 3) void qkv_gemm(
    const u16* __restrict__ Xh, const u16* __restrict__ Xl,
    const u16* __restrict__ Wqh, const u16* __restrict__ Wql,
    const u16* __restrict__ Wkh, const u16* __restrict__ Wkl,
    const u16* __restrict__ Wvh,
    u16* __restrict__ Qh, u16* __restrict__ Ql,
    u16* __restrict__ Kh, u16* __restrict__ Kl,
    u16* __restrict__ VT)
{
    __shared__ __align__(16) u16 S[16384];    // staging 4x4096; epilogue transpose scratch
    u16* const Xhs = &S[0];
    u16* const Xls = &S[4096];
    u16* const Whs = &S[8192];
    u16* const Wls = &S[12288];
    const int tid = threadIdx.x;
    const int wave = tid >> 6, lane = tid & 63, quad = lane >> 4, c16 = lane & 15;
    const int id = blockIdx.x;
    const int nb = (((id >> 3) % 3) << 3) | (id & 7);   // 0..23
    const int m0 = ((id >> 3) / 3) * 128;
    const int mat = nb >> 3;
    const int n0 = (nb & 7) * 128;
    const u16* Bh = (mat == 0) ? Wqh : ((mat == 1) ? Wkh : Wvh);
    const u16* Bl = (mat == 0) ? Wql : Wkl;
    const int nseg = (mat < 2) ? 3 : 1;
    const int wm = (wave >> 1) * 64, wn = (wave & 1) * 64;

    const int srow0 = wave * 32 + (lane >> 2), scol = (lane & 3) * 8;

    f32x4 acc[4][4];
#pragma unroll
    for (int i = 0; i < 4; i++)
#pragma unroll
        for (int j = 0; j < 4; j++) acc[i][j] = (f32x4){0.f, 0.f, 0.f, 0.f};

    for (int kt = 0; kt < 32; kt++) {
        const int kcol = kt * 32;
#pragma unroll
        for (int s = 0; s < 2; s++) {
            int row = srow0 + s * 16;
            size_t go = (size_t)row * 1024 + kcol + scol;
            int lo = row * 32 + scol;
            gl16(Xh + (size_t)m0 * 1024 + go, &Xhs[lo]);
            gl16(Bh + (size_t)n0 * 1024 + go, &Whs[lo]);
            if (nseg == 3) {
                gl16(Xl + (size_t)m0 * 1024 + go, &Xls[lo]);
                gl16(Bl + (size_t)n0 * 1024 + go, &Wls[lo]);
            }
        }
        __syncthreads();
        // fragment-dedup: xh,wh read once, reused for segs {hh, hl, lh}
        bf16x8 xh[4], wh[4];
#pragma unroll
        for (int mt = 0; mt < 4; mt++)
            xh[mt] = *(const bf16x8*)&Xhs[(wm + mt * 16 + c16) * 32 + quad * 8];
#pragma unroll
        for (int nt = 0; nt < 4; nt++)
            wh[nt] = *(const bf16x8*)&Whs[(wn + nt * 16 + c16) * 32 + quad * 8];
#pragma unroll
        for (int mt = 0; mt < 4; mt++)
#pragma unroll
            for (int nt = 0; nt < 4; nt++)
                acc[mt][nt] = MFMA(xh[mt], wh[nt], acc[mt][nt]);
        if (nseg == 3) {
            bf16x8 wl[4];
#pragma unroll
            for (int nt = 0; nt < 4; nt++)
                wl[nt] = *(const bf16x8*)&Wls[(wn + nt * 16 + c16) * 32 + quad * 8];
#pragma unroll
            for (int mt = 0; mt < 4; mt++)
#pragma unroll
                for (int nt = 0; nt < 4; nt++)
                    acc[mt][nt] = MFMA(xh[mt], wl[nt], acc[mt][nt]);
            bf16x8 xl[4];
#pragma unroll
            for (int mt = 0; mt < 4; mt++)
                xl[mt] = *(const bf16x8*)&Xls[(wm + mt * 16 + c16) * 32 + quad * 8];
#pragma unroll
            for (int mt = 0; mt < 4; mt++)
#pragma unroll
                for (int nt = 0; nt < 4; nt++)
                    acc[mt][nt] = MFMA(xl[mt], wh[nt], acc[mt][nt]);
        }
        __syncthreads();
    }

    if (mat == 2) {
        // V epilogue: wave-private LDS transpose -> coalesced VT stores.
        // T2[n 0..63][m-half 0..31] u16 at wavebase + n*40 + m  (40: 16B-aligned rows, 2-way banks)
        u16* const T2 = &S[wave * 4096];
        const int nglob = n0 + wn + lane;
        const int hh = nglob >> 6, dh = nglob & 63;
        const int bh64 = ((m0 >> 11) * 16 + hh) * 64 + dh;   // m0 is 128-aligned; b = m0>>11
        u16* const vrow = VT + (size_t)bh64 * 2048 + (m0 & 2047) + wm;
#pragma unroll
        for (int half = 0; half < 2; half++) {
#pragma unroll
            for (int mt2 = 0; mt2 < 2; mt2++) {
                int mt = half * 2 + mt2;
#pragma unroll
                for (int nt = 0; nt < 4; nt++) {
                    uint2 d;
                    d.x = pk2(acc[mt][nt][0], acc[mt][nt][1]);
                    d.y = pk2(acc[mt][nt][2], acc[mt][nt][3]);
                    *(uint2*)&T2[(nt * 16 + c16) * 40 + mt2 * 16 + quad * 4] = d;
                }
            }
            // read row n=lane (32 u16 = 64B) and store contiguous to VT
#pragma unroll
            for (int c = 0; c < 4; c++) {
                uint4 d = *(const uint4*)&T2[lane * 40 + c * 8];
                *(uint4*)&vrow[half * 32 + c * 8] = d;
            }
        }
    } else {
        // fold 1/sqrt(Dh) AND 2*log2e into Q: attn computes e^{2x} = 2^{sa} directly
        const float scale = (mat == 0) ? 0.36067376022224085f : 1.f;
#pragma unroll
        for (int mt = 0; mt < 4; mt++) {
#pragma unroll
            for (int nt = 0; nt < 4; nt++) {
#pragma unroll
                for (int reg = 0; reg < 4; reg++) {
                    int mm = m0 + wm + mt * 16 + quad * 4 + reg;
                    int n = n0 + wn + nt * 16 + c16;
                    int b_ = mm >> 11, l = mm & 2047;
                    int h = n >> 6, dh = n & 63;
                    float v = acc[mt][nt][reg] * scale;
                    u16 hi, lo; split1(v, hi, lo);
                    int idx = ((b_ * 16 + h) * 2048 + l) * 64 + dh;
                    if (mat == 0) { Qh[idx] = hi; Ql[idx] = lo; }
                    else          { Kh[idx] = hi; Kl[idx] = lo; }
                }
            }
        }
    }
}

// ---------------- Kernel 2: flash attention, DOUBLE-Q (128 rows/block) ----------------
// grid (32 bh, 16 Y), 512 threads (8 waves). j = Y<8 ? Y : 23-Y; q0 = 128j;
// kb = 0..2j+1. Wave w owns q rows [q0+16w, q0+16w+16). K staging/barrier/ds-reads
// shared across 8 waves. LDS 48KB -> 2 blocks/CU. Inner per-wave code = R7.
__global__ __launch_bounds__(512, 4) void attn(
    const u16* __restrict__ Qh, const u16* __restrict__ Ql,
    const u16* __restrict__ Kh, const u16* __restrict__ Kl,
    const u16* __restrict__ VT, const int* __restrict__ AM,
    float* __restrict__ Out)
{
    __shared__ __align__(16) u16 Khs[2][4096];
    __shared__ __align__(16) u16 Kls[2][4096];
    __shared__ __align__(16) u16 Ps[8192];   // [sub(2)][128 rows][32 kc]

    const int tid = threadIdx.x, wave = tid >> 6, lane = tid & 63;
    const int quad = lane >> 4, c16 = lane & 15;
    const int bh = blockIdx.x;                 // fast dim => bh pinned to an XCD
    const int Y = blockIdx.y;
    const int j = (Y < 8) ? Y : 23 - Y;        // pair {Y, Y+8} totals = 34 const
    const int qt_last = 2 * j + 1;
    const int q0 = j * 128;
    const int b_ = bh >> 4;
    const size_t base = (size_t)bh * 2048 * 64;

    // 512-thread stageK mapping: slice = wave (0..7): sub = wave>>2,
    // row = (wave&3)*16 + lane>>2, chunk = (lane&3)*8. dest = wavebase + lane*16B.
    const int ssub = wave >> 2;
    const int srow = (wave & 3) * 16 + (lane >> 2);
    const int scol = (lane & 3) * 8;                                   // linear LDS chunk
    const int gscol = (((lane & 3) ^ ((lane >> 3) & 3))) * 8;          // swizzled GLOBAL chunk
    const int rcsw = ((c16 >> 1) & 3) * 8;                             // read-side XOR (u16 units)

    auto stageK = [&](int k0, int buf) {
        const size_t go = base + (size_t)(k0 + srow) * 64 + ssub * 32 + gscol;
        const int lo = ssub * 2048 + srow * 32 + scol;
        gl16(Kh + go, &Khs[buf][lo]);
        gl16(Kl + go, &Kls[buf][lo]);
    };

    // Q fragments direct from global (A-layout rows contiguous: 16B/lane)
    const size_t qrow = base + (size_t)(q0 + wave * 16 + c16) * 64 + quad * 8;
    bf16x8 qh0 = *(const bf16x8*)&Qh[qrow];
    bf16x8 qh1 = *(const bf16x8*)&Qh[qrow + 32];
    bf16x8 ql0 = *(const bf16x8*)&Ql[qrow];
    bf16x8 ql1 = *(const bf16x8*)&Ql[qrow + 32];

    float rsl[4] = {0.f, 0.f, 0.f, 0.f};
    f32x4 o[4];
#pragma unroll
    for (int r = 0; r < 4; r++) o[r] = (f32x4){0.f, 0.f, 0.f, 0.f};

    stageK(0, 0);
    int cur = 0;
    for (int kb = 0; kb <= qt_last; kb++) {
        const int k0 = kb * 64;
        __syncthreads();                         // Khs[cur] landed; old reads done
        if (kb + 1 <= qt_last) stageK(k0 + 64, cur ^ 1);

        // HOISTED: mask + V fragments issued before QK so latency is covered
        int mk[4];
#pragma unroll
        for (int nt = 0; nt < 4; nt++)
            mk[nt] = AM[b_ * 2048 + k0 + nt * 16 + c16];
        bf16x8 vf[4][2];
#pragma unroll
        for (int dt = 0; dt < 4; dt++) {
            const size_t vrow = (size_t)(bh * 64 + dt * 16 + c16) * 2048 + k0 + quad * 8;
            vf[dt][0] = *(const bf16x8*)&VT[vrow];
            vf[dt][1] = *(const bf16x8*)&VT[vrow + 32];
        }

        float p[4][4];
#pragma unroll
        for (int nt = 0; nt < 4; nt++) {
            // swizzled read: chunk = quad ^ ((c16>>1)&3)
            const int krd = (nt * 16 + c16) * 32 + ((quad * 8) ^ rcsw);
            bf16x8 kh0 = *(const bf16x8*)&Khs[cur][krd];
            bf16x8 kh1 = *(const bf16x8*)&Khs[cur][2048 + krd];
            bf16x8 kl0 = *(const bf16x8*)&Kls[cur][krd];
            bf16x8 kl1 = *(const bf16x8*)&Kls[cur][2048 + krd];
            f32x4 sa = (f32x4){0.f, 0.f, 0.f, 0.f};
            sa = MFMA(qh0, kh0, sa);
            sa = MFMA(qh1, kh1, sa);
            sa = MFMA(ql0, kh0, sa);
            sa = MFMA(ql1, kh1, sa);
            sa = MFMA(qh0, kl0, sa);
            sa = MFMA(qh1, kl1, sa);
            const int key = k0 + nt * 16 + c16;
            const bool mok = (mk[nt] != 0);
#pragma unroll
            for (int reg = 0; reg < 4; reg++) {
                int qg = q0 + wave * 16 + quad * 4 + reg;
                // sa pre-scaled by 2*log2e/8 via Q => e^{2x} = 2^{sa}
                float x = sa[reg];
                float e1 = fexp2(x);                     // inf-safe (p->1)
                float r  = __builtin_amdgcn_rcpf(e1 + 1.f);
                float pv = fexp2(-86.561702453337804f * r);  // e^{30 tanh(x)-30}
                bool keep = mok && (key <= qg);          // exact causal (covers tail tiles)
                pv = keep ? pv : 0.f;
                p[nt][reg] = pv;
                rsl[reg] += pv;
            }
        }

        // P: C-layout -> A-layout via wave-private LDS rows (in-order DS pipe)
#pragma unroll
        for (int nt = 0; nt < 4; nt++) {
            int kl_ = nt * 16 + c16, sub = kl_ >> 5, kc = kl_ & 31;
#pragma unroll
            for (int reg = 0; reg < 4; reg++)
                Ps[sub * 4096 + (wave * 16 + quad * 4 + reg) * 32 + kc] = bf16rne(p[nt][reg]);
        }
        bf16x8 p0 = *(const bf16x8*)&Ps[(wave * 16 + c16) * 32 + quad * 8];
        bf16x8 p1 = *(const bf16x8*)&Ps[4096 + (wave * 16 + c16) * 32 + quad * 8];
#pragma unroll
        for (int dt = 0; dt < 4; dt++) {
            o[dt] = MFMA(p0, vf[dt][0], o[dt]);
            o[dt] = MFMA(p1, vf[dt][1], o[dt]);
        }
        cur ^= 1;
    }

    // epilogue: row-sum over the 16 key-lanes of the quad, normalize, write f32 Out
    float inv[4];
#pragma unroll
    for (int reg = 0; reg < 4; reg++) {
        float v = rsl[reg];
#pragma unroll
        for (int off = 1; off < 16; off <<= 1)
            v += __shfl_xor(v, off);
        inv[reg] = __builtin_amdgcn_rcpf(v);
    }
    const int h = bh & 15;
#pragma unroll
    for (int dt = 0; dt < 4; dt++)
#pragma unroll
        for (int reg = 0; reg < 4; reg++) {
            int row = q0 + wave * 16 + quad * 4 + reg;
            Out[((size_t)(b_ * 2048 + row)) * 1024 + h * 64 + dt * 16 + c16]
                = o[dt][reg] * inv[reg];
        }
}

extern "C" void kernel_launch(void* const* d_in, const int* in_sizes, int n_in,
                              void* d_out, int out_size, void* d_ws, size_t ws_size,
                              hipStream_t stream) {
    const float* X  = (const float*)d_in[0];
    const int*   AM = (const int*)d_in[1];
    const float* Wq = (const float*)d_in[2];
    const float* Wk = (const float*)d_in[3];
    const float* Wv = (const float*)d_in[4];
    float* out = (float*)d_out;

    const size_t NE = (size_t)2 * 16 * 2048 * 64;   // 4.19M elems
    const size_t WN = (size_t)1024 * 1024;
    u16* Qh  = (u16*)d_ws;
    u16* Ql  = Qh + NE;
    u16* Kh  = Ql + NE;
    u16* Kl  = Kh + NE;
    u16* VT  = Kl + NE;
    u16* Xh  = VT + NE;
    u16* Xl  = Xh + NE;
    u16* Wqh = Xl + NE;
    u16* Wql = Wqh + WN;
    u16* Wkh = Wql + WN;
    u16* Wkl = Wkh + WN;
    u16* Wvh = Wkl + WN;     // ~69.2 MB total

    presplit<<<7168, 256, 0, stream>>>(X, Wq, Wk, Wv, Xh, Xl, Wqh, Wql, Wkh, Wkl, Wvh);
    qkv_gemm<<<768, 256, 0, stream>>>(Xh, Xl, Wqh, Wql, Wkh, Wkl, Wvh,
                                      Qh, Ql, Kh, Kl, VT);
    attn<<<dim3(32, 16), 512, 0, stream>>>(Qh, Ql, Kh, Kl, VT, AM, out);
}

// Round 12
// 224.440 us; speedup vs baseline: 1.1109x; 1.1109x over previous
//
#include <hip/hip_runtime.h>
#include <hip/hip_bf16.h>

// B=2, L=2048, D=1024, H=16, Dh=64. fp32 in/out, int32 mask. ref = full-fp32 np.
// ===== VERIFIED BEST CONFIGURATION (R7, 230.2us) — restored after R8-R11 probes =====
//  K0 presplit: X,Wq,Wk -> (hi,lo) bf16; Wv -> bf16.  (~10us, HBM-bound)
//  K1 qkv_gemm: 128x128 tile, 32 k-iters, 4-tensor staging (Xh,Xl,Wh,Wl) in 32KB
//     LDS, fragment-dedup (16 ds_read_b128/kt for 48 MFMA). V epilogue via
//     wave-private LDS transpose. Q epilogue folds 2*log2e/8 (exp2 softmax).
//     (~63-69us = ~872 TF, at the m97-structure ceiling.)
//  K2 attn: grid (32 bh, 32 y), 256 thr, 4 blocks/CU. bh = blockIdx.x pins XCD.
//     QUAD-BALANCED y->qt: CU-resident quad {y0,y0+8,y0+16,y0+24} -> qt
//     {31-y0, 16+y0, 15-y0, y0} = 66 k-units/CU constant. Kh+Kl LDS dbuf
//     XOR-swizzled; hoisted V/mask; Ps transpose (linear); bounded softmax
//     p = e^{30 tanh(x)-30}; in-register normalize; f32 Out direct. (~96.5us)
//  SESSION RULES (each backed by a measured regression):
//   - QK-side MFMA operands MUST be LDS-staged one iter ahead; per-iter global
//     loads on that path cost ~55us (R1/R8/R9 all ~151us).
//   - 4 blocks/CU of 256 thr beats 2 blocks of 512: inter-block overlap at the
//     staging barrier dominates per-iter fixed-cost amortization (R11 -20us).
//   - Static XCD-pinned placement; dynamic queues destroy L2 locality (R8 -55us).
//   - No device-scope fences in L2-resident kernels (R4: -290us).
//   - launch_bounds must not force VGPR below live-set (R5: spill, -130us).
//   - Inter-kernel overhead (~55us) is fixed, not per-launch (R6).
//   - SQ_LDS_BANK_CONFLICT floor 2.70M is insensitive to K/Ps swizzles (R10).
//  MFMA C-layout: row=quad*4+reg, col=lane&15 [m89/m91]; A/B-layout: [lane&15][quad*8+j] [m120].

typedef unsigned short u16;
typedef __bf16 bf16x8 __attribute__((ext_vector_type(8)));
typedef float f32x4 __attribute__((ext_vector_type(4)));

#define MFMA(a, b, c) __builtin_amdgcn_mfma_f32_16x16x32_bf16(a, b, c, 0, 0, 0)

__device__ __forceinline__ u16 bf16rne(float f) {
    unsigned int u = __float_as_uint(f);
    u += 0x7fffu + ((u >> 16) & 1u);
    return (u16)(u >> 16);
}
__device__ __forceinline__ float bf16f(u16 h) {
    return __uint_as_float(((unsigned int)h) << 16);
}
__device__ __forceinline__ void split1(float f, u16& hi, u16& lo) {
    hi = bf16rne(f);
    lo = bf16rne(f - bf16f(hi));
}
__device__ __forceinline__ unsigned int pk2(float a, float b) {   // v_cvt_pk_bf16_f32 (RNE)
    __hip_bfloat162 t = __float22bfloat162_rn(float2{a, b});
    return *(unsigned int*)&t;
}
__device__ __forceinline__ float fexp2(float x) {                 // 2^x, raw v_exp_f32
#if __has_builtin(__builtin_amdgcn_exp2f)
    return __builtin_amdgcn_exp2f(x);
#else
    return __expf(x * 0.6931471805599453f);
#endif
}

// async global->LDS, 16B per lane. LDS dest must be uniform_base + lane*16.
__device__ __forceinline__ void gl16(const u16* g, u16* l) {
    __builtin_amdgcn_global_load_lds(
        (const __attribute__((address_space(1))) unsigned int*)g,
        (__attribute__((address_space(3))) unsigned int*)l, 16, 0, 0);
}

// ---------------- Kernel 0: pre-split fp32 -> bf16 hi/lo ----------------
__global__ __launch_bounds__(256) void presplit(
    const float* __restrict__ X, const float* __restrict__ Wq,
    const float* __restrict__ Wk, const float* __restrict__ Wv,
    u16* __restrict__ Xh, u16* __restrict__ Xl,
    u16* __restrict__ Wqh, u16* __restrict__ Wql,
    u16* __restrict__ Wkh, u16* __restrict__ Wkl,
    u16* __restrict__ Wvh)
{
    int i = blockIdx.x * 256 + threadIdx.x;
    const float* src; u16 *dh, *dl; int off;
    if (i < 1048576)      { src = X;  dh = Xh;  dl = Xl;      off = i; }
    else if (i < 1310720) { src = Wq; dh = Wqh; dl = Wql;     off = i - 1048576; }
    else if (i < 1572864) { src = Wk; dh = Wkh; dl = Wkl;     off = i - 1310720; }
    else                  { src = Wv; dh = Wvh; dl = nullptr; off = i - 1572864; }
    float4 v = ((const float4*)src)[off];
    ushort4 h, l;
    split1(v.x, h.x, l.x); split1(v.y, h.y, l.y);
    split1(v.z, h.z, l.z); split1(v.w, h.w, l.w);
    ((ushort4*)dh)[off] = h;
    if (dl) ((ushort4*)dl)[off] = l;
}

// ---------------- Kernel 1: QKV GEMM (4-tensor staging, frag-dedup) ----------------
// 768 blocks; swizzle keeps all m-blocks of one n-block on one XCD.
__global__ __launch_bounds__(256, 3) void qkv_gemm(
    const u16* __restrict__ Xh, const u16* __restrict__ Xl,
    const u16* __restrict__ Wqh, const u16* __restrict__ Wql,
    const u16* __restrict__ Wkh, const u16* __restrict__ Wkl,
    const u16* __restrict__ Wvh,
    u16* __restrict__ Qh, u16* __restrict__ Ql,
    u16* __restrict__ Kh, u16* __restrict__ Kl,
    u16* __restrict__ VT)
{
    __shared__ __align__(16) u16 S[16384];    // staging 4x4096; epilogue transpose scratch
    u16* const Xhs = &S[0];
    u16* const Xls = &S[4096];
    u16* const Whs = &S[8192];
    u16* const Wls = &S[12288];
    const int tid = threadIdx.x;
    const int wave = tid >> 6, lane = tid & 63, quad = lane >> 4, c16 = lane & 15;
    const int id = blockIdx.x;
    const int nb = (((id >> 3) % 3) << 3) | (id & 7);   // 0..23
    const int m0 = ((id >> 3) / 3) * 128;
    const int mat = nb >> 3;
    const int n0 = (nb & 7) * 128;
    const u16* Bh = (mat == 0) ? Wqh : ((mat == 1) ? Wkh : Wvh);
    const u16* Bl = (mat == 0) ? Wql : Wkl;
    const int nseg = (mat < 2) ? 3 : 1;
    const int wm = (wave >> 1) * 64, wn = (wave & 1) * 64;

    const int srow0 = wave * 32 + (lane >> 2), scol = (lane & 3) * 8;

    f32x4 acc[4][4];
#pragma unroll
    for (int i = 0; i < 4; i++)
#pragma unroll
        for (int j = 0; j < 4; j++) acc[i][j] = (f32x4){0.f, 0.f, 0.f, 0.f};

    for (int kt = 0; kt < 32; kt++) {
        const int kcol = kt * 32;
#pragma unroll
        for (int s = 0; s < 2; s++) {
            int row = srow0 + s * 16;
            size_t go = (size_t)row * 1024 + kcol + scol;
            int lo = row * 32 + scol;
            gl16(Xh + (size_t)m0 * 1024 + go, &Xhs[lo]);
            gl16(Bh + (size_t)n0 * 1024 + go, &Whs[lo]);
            if (nseg == 3) {
                gl16(Xl + (size_t)m0 * 1024 + go, &Xls[lo]);
                gl16(Bl + (size_t)n0 * 1024 + go, &Wls[lo]);
            }
        }
        __syncthreads();
        // fragment-dedup: xh,wh read once, reused for segs {hh, hl, lh}
        bf16x8 xh[4], wh[4];
#pragma unroll
        for (int mt = 0; mt < 4; mt++)
            xh[mt] = *(const bf16x8*)&Xhs[(wm + mt * 16 + c16) * 32 + quad * 8];
#pragma unroll
        for (int nt = 0; nt < 4; nt++)
            wh[nt] = *(const bf16x8*)&Whs[(wn + nt * 16 + c16) * 32 + quad * 8];
#pragma unroll
        for (int mt = 0; mt < 4; mt++)
#pragma unroll
            for (int nt = 0; nt < 4; nt++)
                acc[mt][nt] = MFMA(xh[mt], wh[nt], acc[mt][nt]);
        if (nseg == 3) {
            bf16x8 wl[4];
#pragma unroll
            for (int nt = 0; nt < 4; nt++)
                wl[nt] = *(const bf16x8*)&Wls[(wn + nt * 16 + c16) * 32 + quad * 8];
#pragma unroll
            for (int mt = 0; mt < 4; mt++)
#pragma unroll
                for (int nt = 0; nt < 4; nt++)
                    acc[mt][nt] = MFMA(xh[mt], wl[nt], acc[mt][nt]);
            bf16x8 xl[4];
#pragma unroll
            for (int mt = 0; mt < 4; mt++)
                xl[mt] = *(const bf16x8*)&Xls[(wm + mt * 16 + c16) * 32 + quad * 8];
#pragma unroll
            for (int mt = 0; mt < 4; mt++)
#pragma unroll
                for (int nt = 0; nt < 4; nt++)
                    acc[mt][nt] = MFMA(xl[mt], wh[nt], acc[mt][nt]);
        }
        __syncthreads();
    }

    if (mat == 2) {
        // V epilogue: wave-private LDS transpose -> coalesced VT stores.
        // T2[n 0..63][m-half 0..31] u16 at wavebase + n*40 + m  (40: 16B-aligned rows, 2-way banks)
        u16* const T2 = &S[wave * 4096];
        const int nglob = n0 + wn + lane;
        const int hh = nglob >> 6, dh = nglob & 63;
        const int bh64 = ((m0 >> 11) * 16 + hh) * 64 + dh;   // m0 is 128-aligned; b = m0>>11
        u16* const vrow = VT + (size_t)bh64 * 2048 + (m0 & 2047) + wm;
#pragma unroll
        for (int half = 0; half < 2; half++) {
#pragma unroll
            for (int mt2 = 0; mt2 < 2; mt2++) {
                int mt = half * 2 + mt2;
#pragma unroll
                for (int nt = 0; nt < 4; nt++) {
                    uint2 d;
                    d.x = pk2(acc[mt][nt][0], acc[mt][nt][1]);
                    d.y = pk2(acc[mt][nt][2], acc[mt][nt][3]);
                    *(uint2*)&T2[(nt * 16 + c16) * 40 + mt2 * 16 + quad * 4] = d;
                }
            }
            // read row n=lane (32 u16 = 64B) and store contiguous to VT
#pragma unroll
            for (int c = 0; c < 4; c++) {
                uint4 d = *(const uint4*)&T2[lane * 40 + c * 8];
                *(uint4*)&vrow[half * 32 + c * 8] = d;
            }
        }
    } else {
        // fold 1/sqrt(Dh) AND 2*log2e into Q: attn computes e^{2x} = 2^{sa} directly
        const float scale = (mat == 0) ? 0.36067376022224085f : 1.f;
#pragma unroll
        for (int mt = 0; mt < 4; mt++) {
#pragma unroll
            for (int nt = 0; nt < 4; nt++) {
#pragma unroll
                for (int reg = 0; reg < 4; reg++) {
                    int mm = m0 + wm + mt * 16 + quad * 4 + reg;
                    int n = n0 + wn + nt * 16 + c16;
                    int b_ = mm >> 11, l = mm & 2047;
                    int h = n >> 6, dh = n & 63;
                    float v = acc[mt][nt][reg] * scale;
                    u16 hi, lo; split1(v, hi, lo);
                    int idx = ((b_ * 16 + h) * 2048 + l) * 64 + dh;
                    if (mat == 0) { Qh[idx] = hi; Ql[idx] = lo; }
                    else          { Kh[idx] = hi; Kl[idx] = lo; }
                }
            }
        }
    }
}

// ---------------- Kernel 2: flash attention, one q-tile per block ----------------
// grid (32 bh, 32 y). QUAD-BALANCED map y->qt. kb = 0..qt. LDS 40KB -> 4 blocks/CU.
__global__ __launch_bounds__(256, 4) void attn(
    const u16* __restrict__ Qh, const u16* __restrict__ Ql,
    const u16* __restrict__ Kh, const u16* __restrict__ Kl,
    const u16* __restrict__ VT, const int* __restrict__ AM,
    float* __restrict__ Out)
{
    __shared__ __align__(16) u16 Khs[2][4096];
    __shared__ __align__(16) u16 Kls[2][4096];
    __shared__ __align__(16) u16 Ps[4096];

    const int tid = threadIdx.x, wave = tid >> 6, lane = tid & 63;
    const int quad = lane >> 4, c16 = lane & 15;
    const int bh = blockIdx.x;                 // fast dim => bh pinned to an XCD
    // quad-balanced qt: CU-resident y-quad {y0,y0+8,y0+16,y0+24} -> qt sum 62 (+4 = 66 units)
    const int y = blockIdx.y;
    const int y0 = y & 7, g = y >> 3;
    const int qt = (g == 0) ? 31 - y0 : (g == 1) ? 16 + y0 : (g == 2) ? 15 - y0 : y0;
    const int q0 = qt * 64;
    const int b_ = bh >> 4;
    const size_t base = (size_t)bh * 2048 * 64;

    const int swsub[2] = { (wave * 2) >> 2, (wave * 2 + 1) >> 2 };
    const int swrow[2] = { ((wave * 2) & 3) * 16 + (lane >> 2), ((wave * 2 + 1) & 3) * 16 + (lane >> 2) };
    const int scol = (lane & 3) * 8;                                   // LDS chunk (linear dest)
    const int gscol = (((lane & 3) ^ ((lane >> 3) & 3))) * 8;          // swizzled GLOBAL chunk
    const int rcsw = ((c16 >> 1) & 3) * 8;                             // read-side XOR (u16 units)

    auto stageK = [&](int k0, int buf) {
        const u16* Kht = Kh + base + (size_t)k0 * 64;
        const u16* Klt = Kl + base + (size_t)k0 * 64;
#pragma unroll
        for (int s = 0; s < 2; s++) {
            int sub = swsub[s], row = swrow[s];
            int lo = sub * 2048 + row * 32 + scol;
            gl16(Kht + (size_t)row * 64 + sub * 32 + gscol, &Khs[buf][lo]);
            gl16(Klt + (size_t)row * 64 + sub * 32 + gscol, &Kls[buf][lo]);
        }
    };

    // Q fragments direct from global (A-layout rows contiguous: 16B/lane)
    const size_t qrow = base + (size_t)(q0 + wave * 16 + c16) * 64 + quad * 8;
    bf16x8 qh0 = *(const bf16x8*)&Qh[qrow];
    bf16x8 qh1 = *(const bf16x8*)&Qh[qrow + 32];
    bf16x8 ql0 = *(const bf16x8*)&Ql[qrow];
    bf16x8 ql1 = *(const bf16x8*)&Ql[qrow + 32];

    float rsl[4] = {0.f, 0.f, 0.f, 0.f};
    f32x4 o[4];
#pragma unroll
    for (int r = 0; r < 4; r++) o[r] = (f32x4){0.f, 0.f, 0.f, 0.f};

    stageK(0, 0);
    int cur = 0;
    for (int kb = 0; kb <= qt; kb++) {
        const int k0 = kb * 64;
        __syncthreads();                         // Khs[cur] landed; old reads done
        if (kb + 1 <= qt) stageK(k0 + 64, cur ^ 1);

        // HOISTED: mask + V fragments issued before QK so latency is covered
        int mk[4];
#pragma unroll
        for (int nt = 0; nt < 4; nt++)
            mk[nt] = AM[b_ * 2048 + k0 + nt * 16 + c16];
        bf16x8 vf[4][2];
#pragma unroll
        for (int dt = 0; dt < 4; dt++) {
            const size_t vrow = (size_t)(bh * 64 + dt * 16 + c16) * 2048 + k0 + quad * 8;
            vf[dt][0] = *(const bf16x8*)&VT[vrow];
            vf[dt][1] = *(const bf16x8*)&VT[vrow + 32];
        }
        const bool interior = (kb < qt);

        float p[4][4];
#pragma unroll
        for (int nt = 0; nt < 4; nt++) {
            // swizzled read: chunk = quad ^ ((c16>>1)&3)
            const int krd = (nt * 16 + c16) * 32 + ((quad * 8) ^ rcsw);
            bf16x8 kh0 = *(const bf16x8*)&Khs[cur][krd];
            bf16x8 kh1 = *(const bf16x8*)&Khs[cur][2048 + krd];
            bf16x8 kl0 = *(const bf16x8*)&Kls[cur][krd];
            bf16x8 kl1 = *(const bf16x8*)&Kls[cur][2048 + krd];
            f32x4 sa = (f32x4){0.f, 0.f, 0.f, 0.f};
            sa = MFMA(qh0, kh0, sa);
            sa = MFMA(qh1, kh1, sa);
            sa = MFMA(ql0, kh0, sa);
            sa = MFMA(ql1, kh1, sa);
            sa = MFMA(qh0, kl0, sa);
            sa = MFMA(qh1, kl1, sa);
            const int key = k0 + nt * 16 + c16;
            const bool mok = (mk[nt] != 0);
#pragma unroll
            for (int reg = 0; reg < 4; reg++) {
                int qg = q0 + wave * 16 + quad * 4 + reg;
                // sa pre-scaled by 2*log2e/8 via Q => e^{2x} = 2^{sa}
                float x = sa[reg];
                float e1 = fexp2(x);                     // inf-safe (p->1)
                float r  = __builtin_amdgcn_rcpf(e1 + 1.f);
                float pv = fexp2(-86.561702453337804f * r);  // e^{30 tanh(x)-30}
                bool keep = mok && (interior || key <= qg);
                pv = keep ? pv : 0.f;
                p[nt][reg] = pv;
                rsl[reg] += pv;
            }
        }

        // P: C-layout -> A-layout via wave-private LDS rows (in-order DS pipe)
#pragma unroll
        for (int nt = 0; nt < 4; nt++) {
            int kl_ = nt * 16 + c16, sub = kl_ >> 5, kc = kl_ & 31;
#pragma unroll
            for (int reg = 0; reg < 4; reg++)
                Ps[sub * 2048 + (wave * 16 + quad * 4 + reg) * 32 + kc] = bf16rne(p[nt][reg]);
        }
        bf16x8 p0 = *(const bf16x8*)&Ps[(wave * 16 + c16) * 32 + quad * 8];
        bf16x8 p1 = *(const bf16x8*)&Ps[2048 + (wave * 16 + c16) * 32 + quad * 8];
#pragma unroll
        for (int dt = 0; dt < 4; dt++) {
            o[dt] = MFMA(p0, vf[dt][0], o[dt]);
            o[dt] = MFMA(p1, vf[dt][1], o[dt]);
        }
        cur ^= 1;
    }

    // epilogue: row-sum over the 16 key-lanes of the quad, normalize, write f32 Out
    float inv[4];
#pragma unroll
    for (int reg = 0; reg < 4; reg++) {
        float v = rsl[reg];
#pragma unroll
        for (int off = 1; off < 16; off <<= 1)
            v += __shfl_xor(v, off);
        inv[reg] = __builtin_amdgcn_rcpf(v);
    }
    const int h = bh & 15;
#pragma unroll
    for (int dt = 0; dt < 4; dt++)
#pragma unroll
        for (int reg = 0; reg < 4; reg++) {
            int row = q0 + wave * 16 + quad * 4 + reg;
            Out[((size_t)(b_ * 2048 + row)) * 1024 + h * 64 + dt * 16 + c16]
                = o[dt][reg] * inv[reg];
        }
}

extern "C" void kernel_launch(void* const* d_in, const int* in_sizes, int n_in,
                              void* d_out, int out_size, void* d_ws, size_t ws_size,
                              hipStream_t stream) {
    const float* X  = (const float*)d_in[0];
    const int*   AM = (const int*)d_in[1];
    const float* Wq = (const float*)d_in[2];
    const float* Wk = (const float*)d_in[3];
    const float* Wv = (const float*)d_in[4];
    float* out = (float*)d_out;

    const size_t NE = (size_t)2 * 16 * 2048 * 64;   // 4.19M elems
    const size_t WN = (size_t)1024 * 1024;
    u16* Qh  = (u16*)d_ws;
    u16* Ql  = Qh + NE;
    u16* Kh  = Ql + NE;
    u16* Kl  = Kh + NE;
    u16* VT  = Kl + NE;
    u16* Xh  = VT + NE;
    u16* Xl  = Xh + NE;
    u16* Wqh = Xl + NE;
    u16* Wql = Wqh + WN;
    u16* Wkh = Wql + WN;
    u16* Wkl = Wkh + WN;
    u16* Wvh = Wkl + WN;     // ~69.2 MB total

    presplit<<<7168, 256, 0, stream>>>(X, Wq, Wk, Wv, Xh, Xl, Wqh, Wql, Wkh, Wkl, Wvh);
    qkv_gemm<<<768, 256, 0, stream>>>(Xh, Xl, Wqh, Wql, Wkh, Wkl, Wvh,
                                      Qh, Ql, Kh, Kl, VT);
    attn<<<dim3(32, 32), 256, 0, stream>>>(Qh, Ql, Kh, Kl, VT, AM, out);
}